// Round 1
// baseline (31.157 us; speedup 1.0000x reference)
//
#include <hip/hip_runtime.h>

// Problem constants (fixed by the reference setup)
#define BB 8
#define LL 4096
#define DD 1024
#define KK 2048

// One block (1024 threads) per batch. Stable compaction via prefix scan:
// boundary positions get rank = #boundaries before them; non-boundary get
// rank = num_tokens + #non-boundaries before them. Scatter i -> idx[rank]
// for rank < K. Reproduces argsort(i + (~bm)*L)[:K] exactly (unique keys).
__global__ void build_idx_kernel(const int* __restrict__ bm,
                                 int* __restrict__ idx,
                                 int* __restrict__ ntok) {
    __shared__ int tsum[1024];
    const int b   = blockIdx.x;
    const int tid = threadIdx.x;
    const int* m  = bm + (size_t)b * LL;

    constexpr int PER = LL / 1024;  // 4 elements per thread
    const int base = tid * PER;
    int local[PER];
    int s = 0;
#pragma unroll
    for (int j = 0; j < PER; ++j) {
        local[j] = (m[base + j] != 0);
        s += local[j];
    }
    tsum[tid] = s;
    __syncthreads();

    // Hillis-Steele inclusive scan over thread sums
    for (int off = 1; off < 1024; off <<= 1) {
        int v = (tid >= off) ? tsum[tid - off] : 0;
        __syncthreads();
        tsum[tid] += v;
        __syncthreads();
    }

    const int total = tsum[1023];          // num_tokens for this batch
    const int excl  = tsum[tid] - s;       // exclusive prefix for this chunk
    if (tid == 0) ntok[b] = total;

    int* ib = idx + (size_t)b * KK;
    int brank = excl;
#pragma unroll
    for (int j = 0; j < PER; ++j) {
        const int i = base + j;
        if (local[j]) {
            if (brank < KK) ib[brank] = i;
            ++brank;
        } else {
            const int nr = total + (i - brank);  // i - brank = #non-boundary before i
            if (nr < KK) ib[nr] = i;
        }
    }
}

// One block per output row; 256 threads x float4 = 4096 B row copy.
__global__ void gather_kernel(const float4* __restrict__ src,
                              const int* __restrict__ idx,
                              float4* __restrict__ dst) {
    const int row = blockIdx.x;            // 0 .. B*K-1
    const int b   = row >> 11;             // row / K (K = 2048)
    const int srow = idx[row];             // idx laid out [B][K] flat
    const float4* s = src + ((size_t)b * LL + srow) * (DD / 4);
    float4*       d = dst + (size_t)row * (DD / 4);
    d[threadIdx.x] = s[threadIdx.x];
}

// next_mask as float 1.0/0.0 (output tuple concatenated flat; mask after hs)
__global__ void mask_kernel(const int* __restrict__ ntok,
                            float* __restrict__ om) {
    const int t = blockIdx.x * blockDim.x + threadIdx.x;  // 0 .. B*K-1
    const int b = t >> 11;
    const int k = t & (KK - 1);
    om[t] = (k < ntok[b]) ? 1.0f : 0.0f;
}

extern "C" void kernel_launch(void* const* d_in, const int* in_sizes, int n_in,
                              void* d_out, int out_size, void* d_ws, size_t ws_size,
                              hipStream_t stream) {
    const float* hs = (const float*)d_in[0];   // (B, L, D) f32
    const int*   bm = (const int*)d_in[1];     // (B, L) bool -> int32
    // d_in[2] (mask) unused; d_in[3] (next_max_seqlen) fixed at K=2048

    float* out_hs   = (float*)d_out;                       // B*K*D floats
    float* out_mask = (float*)d_out + (size_t)BB * KK * DD; // B*K floats

    int* idx  = (int*)d_ws;            // B*K ints
    int* ntok = idx + (size_t)BB * KK; // B ints

    build_idx_kernel<<<BB, 1024, 0, stream>>>(bm, idx, ntok);
    gather_kernel<<<BB * KK, DD / 4, 0, stream>>>((const float4*)hs, idx, (float4*)out_hs);
    mask_kernel<<<(BB * KK) / 256, 256, 0, stream>>>(ntok, out_mask);
}

// Round 2
// 29.474 us; speedup vs baseline: 1.0571x; 1.0571x over previous
//
#include <hip/hip_runtime.h>

// Problem constants (fixed by the reference setup)
#define BB 8
#define LL 4096
#define DD 1024
#define KK 2048

// One block (1024 threads = 16 waves) per batch.
// Stable compaction via hierarchical prefix scan:
//   boundary positions get rank = #boundaries before them;
//   non-boundary positions get rank = num_tokens + #non-boundaries before them.
// Scatter i -> idx[rank] for rank < K. Reproduces argsort(i + (~bm)*L)[:K]
// exactly (keys are unique). Also writes the next_mask output (fused).
__global__ void build_idx_kernel(const int* __restrict__ bm,
                                 int* __restrict__ idx,
                                 float* __restrict__ om) {
    __shared__ int wsum[16];
    const int b    = blockIdx.x;
    const int tid  = threadIdx.x;      // 0..1023
    const int lane = tid & 63;
    const int wave = tid >> 6;         // 0..15

    const int* m = bm + (size_t)b * LL;

    // 4 mask elements per thread, vector load
    const int base = tid * 4;
    const int4 v = *reinterpret_cast<const int4*>(m + base);
    int local[4] = { v.x != 0, v.y != 0, v.z != 0, v.w != 0 };
    const int s = local[0] + local[1] + local[2] + local[3];

    // wave-level inclusive scan of per-thread sums (no barriers)
    int incl = s;
#pragma unroll
    for (int off = 1; off < 64; off <<= 1) {
        const int t = __shfl_up(incl, off, 64);
        if (lane >= off) incl += t;
    }
    if (lane == 63) wsum[wave] = incl;
    __syncthreads();

    // wave 0 scans the 16 wave totals
    if (wave == 0) {
        int wv = (lane < 16) ? wsum[lane] : 0;
#pragma unroll
        for (int off = 1; off < 16; off <<= 1) {
            const int t = __shfl_up(wv, off, 64);
            if (lane >= off) wv += t;
        }
        if (lane < 16) wsum[lane] = wv;   // inclusive wave totals
    }
    __syncthreads();

    const int total   = wsum[15];                    // num_tokens for batch b
    const int waveoff = (wave == 0) ? 0 : wsum[wave - 1];
    int brank = waveoff + incl - s;                  // exclusive boundary rank

    int* ib = idx + (size_t)b * KK;
#pragma unroll
    for (int j = 0; j < 4; ++j) {
        const int i = base + j;
        if (local[j]) {
            if (brank < KK) ib[brank] = i;
            ++brank;
        } else {
            const int nr = total + (i - brank);      // i - brank = #non-bnd before i
            if (nr < KK) ib[nr] = i;
        }
    }

    // fused next_mask write (2048 floats per batch, 2 per thread)
    float* omb = om + (size_t)b * KK;
    omb[tid]        = (tid        < total) ? 1.0f : 0.0f;
    omb[tid + 1024] = (tid + 1024 < total) ? 1.0f : 0.0f;
}

// One block per output row; 256 threads x float4 = 4096 B row copy.
__global__ void __launch_bounds__(256)
gather_kernel(const float4* __restrict__ src,
              const int* __restrict__ idx,
              float4* __restrict__ dst) {
    const int row  = blockIdx.x;           // 0 .. B*K-1
    const int b    = row >> 11;            // row / K (K = 2048)
    const int srow = idx[row];             // idx laid out [B][K] flat
    const float4* s = src + ((size_t)b * LL + srow) * (DD / 4);
    float4*       d = dst + (size_t)row * (DD / 4);
    d[threadIdx.x] = s[threadIdx.x];
}

extern "C" void kernel_launch(void* const* d_in, const int* in_sizes, int n_in,
                              void* d_out, int out_size, void* d_ws, size_t ws_size,
                              hipStream_t stream) {
    const float* hs = (const float*)d_in[0];   // (B, L, D) f32
    const int*   bm = (const int*)d_in[1];     // (B, L) bool -> int32
    // d_in[2] (mask) unused; d_in[3] (next_max_seqlen) fixed at K=2048

    float* out_hs   = (float*)d_out;                        // B*K*D floats
    float* out_mask = (float*)d_out + (size_t)BB * KK * DD; // B*K floats

    int* idx = (int*)d_ws;                 // B*K ints

    build_idx_kernel<<<BB, 1024, 0, stream>>>(bm, idx, out_mask);
    gather_kernel<<<BB * KK, DD / 4, 0, stream>>>((const float4*)hs, idx, (float4*)out_hs);
}

// Round 4
// 29.198 us; speedup vs baseline: 1.0671x; 1.0095x over previous
//
#include <hip/hip_runtime.h>

// Problem constants (fixed by the reference setup)
#define BB 8
#define LL 4096
#define DD 1024
#define KK 2048

#define RPB 8               // output rows per block
#define NWORDS (LL / 64)    // 64 u64 words per batch bitmap

typedef float f32x4 __attribute__((ext_vector_type(4)));

// Single fused kernel. Each block:
//  1) rebuilds the batch's 4096-bit boundary bitmap (16 coalesced loads +
//     __ballot per wave -> 64 u64 words in LDS; mask is L2-resident, cheap),
//  2) prefix-scans the 64 popcounts (one wave, shfl scan),
//  3) selects the source row for each of its 8 output rows: k-th set bit if
//     k < num_tokens, else (k-num_tokens)-th clear bit -- exactly the stable
//     compaction order of argsort(i + (~bm)*L)[:K] (unique keys),
//  4) streams 8 rows x 4 KiB with nontemporal float4 copies, and writes its
//     8 next_mask floats.
__global__ void __launch_bounds__(256)
fused_gather_kernel(const f32x4* __restrict__ src,
                    const int* __restrict__ bm,
                    f32x4* __restrict__ dst,
                    float* __restrict__ om) {
    __shared__ unsigned long long words[NWORDS];
    __shared__ int pre[NWORDS];     // popcounts, then inclusive prefix
    __shared__ int srows[RPB];

    const int blk   = blockIdx.x;          // 0 .. 2047
    const int tid   = threadIdx.x;         // 0 .. 255
    const int lane  = tid & 63;
    const int wave  = tid >> 6;            // 0 .. 3
    const int b     = blk >> 8;            // 256 blocks per batch
    const int kbase = (blk & 255) * RPB;   // k offset within batch

    const int* m = bm + (size_t)b * LL;

    // 1) bitmap build: ballot j in wave w covers positions (j*4+w)*64 + lane
#pragma unroll
    for (int j = 0; j < 16; ++j) {
        const unsigned long long w = __ballot(m[j * 256 + tid] != 0);
        if (lane == 0) {
            const int wi = j * 4 + wave;
            words[wi] = w;
            pre[wi]   = __popcll(w);
        }
    }
    __syncthreads();

    // 2) inclusive scan of 64 word-popcounts (wave 0)
    if (wave == 0) {
        int v = pre[lane];
#pragma unroll
        for (int off = 1; off < 64; off <<= 1) {
            const int t = __shfl_up(v, off, 64);
            if (lane >= off) v += t;
        }
        pre[lane] = v;
    }
    __syncthreads();

    const int total = pre[NWORDS - 1];     // num_tokens for batch b

    // 3) per-row source index selection (threads 0..7)
    if (tid < RPB) {
        const int kb = kbase + tid;
        int lo = 0, hi = NWORDS - 1, r;
        unsigned long long x;
        if (kb < total) {
            // smallest word w with pre[w] > kb
            while (lo < hi) { const int mid = (lo + hi) >> 1; if (pre[mid] > kb) hi = mid; else lo = mid + 1; }
            r = kb - ((lo == 0) ? 0 : pre[lo - 1]);
            x = words[lo];
        } else {
            // clear-bit select: zeros_incl[w] = (w+1)*64 - pre[w]
            const int rz = kb - total;
            while (lo < hi) { const int mid = (lo + hi) >> 1; if ((mid + 1) * 64 - pre[mid] > rz) hi = mid; else lo = mid + 1; }
            r = rz - (lo * 64 - ((lo == 0) ? 0 : pre[lo - 1]));
            x = ~words[lo];
        }
        // select r-th (0-based) set bit of x
        int pos = 0;
#pragma unroll
        for (int sh = 32; sh >= 1; sh >>= 1) {
            const int c = __popcll(x & ((1ull << sh) - 1ull));
            if (r >= c) { r -= c; x >>= sh; pos += sh; }
        }
        srows[tid] = lo * 64 + pos;
        om[(size_t)b * KK + kb] = (kb < total) ? 1.0f : 0.0f;
    }
    __syncthreads();

    // 4) stream 8 rows x 4 KiB (coalesced float4, nontemporal)
    const size_t srcbase = (size_t)b * LL * (DD / 4);
    const size_t dstbase = ((size_t)b * KK + kbase) * (DD / 4);
#pragma unroll
    for (int j = 0; j < RPB; ++j) {
        const f32x4 v = __builtin_nontemporal_load(&src[srcbase + (size_t)srows[j] * (DD / 4) + tid]);
        __builtin_nontemporal_store(v, &dst[dstbase + (size_t)j * (DD / 4) + tid]);
    }
}

extern "C" void kernel_launch(void* const* d_in, const int* in_sizes, int n_in,
                              void* d_out, int out_size, void* d_ws, size_t ws_size,
                              hipStream_t stream) {
    const float* hs = (const float*)d_in[0];   // (B, L, D) f32
    const int*   bm = (const int*)d_in[1];     // (B, L) bool -> int32
    // d_in[2] (mask) unused; d_in[3] (next_max_seqlen) fixed at K=2048

    float* out_hs   = (float*)d_out;                        // B*K*D floats
    float* out_mask = (float*)d_out + (size_t)BB * KK * DD; // B*K floats

    fused_gather_kernel<<<(BB * KK) / RPB, 256, 0, stream>>>(
        (const f32x4*)hs, bm, (f32x4*)out_hs, out_mask);
}